// Round 8
// baseline (577.714 us; speedup 1.0000x reference)
//
#include <hip/hip_runtime.h>

// LSTM forward scan: T=1024, B=16, NH=12, HD=64, NG=4 (i,f,z,o).
// One block per (b,n) chain: 192 blocks x 256 threads; tid = o*4+g.
//
// Lessons carried:
//  * raw `s_waitcnt lgkmcnt(0); s_barrier` — __syncthreads() drains vmcnt(0).
//  * Quad-split dot (R4: 474->382us): lane (o,g) dots all 4 gates over
//    h[16g:16g+16); butterfly combines. 16x less LDS traffic.
//  * Reads-first + store-in-shadow + walking pointers (R5: 382->371us).
//  * R6 FAILURE lesson: hand-written DPP asm needs MANUAL hazard nops —
//    "VALU writes VGPR -> DPP reads it" requires 2 wait states; LLVM's
//    hazard recognizer can't see into inline asm. The fused v_add_f32_dpp
//    reading q2 right after the previous asm wrote it corrupted the dot
//    (absmax 0.84). Fix: `s_nop 1` embedded before each DPP add.
// R7 was an infra failure (container died twice) — this source is the R6
// kernel resubmitted unchanged.
//  * gate exchange = 4 DPP quad-BROADCASTS (builtin, compiler-managed).
//  * butterfly via s_nop-guarded fused v_add_f32_dpp (3 hops).
//  * swb = fma(s_coef,wxv,s_coef*bval); act arg = fma(s_coef,d0,swb).
//  * m2c = fma(K*xf, c_old, K*(xi*xz)) = K*c_new — tanh exp2 starts parallel
//    with the c-update fma; hval = fma(2*xo, rcp, -xo).
//  * SGPR-walked bases for out-store and Wx prefetch.

#define T_SEQ 1024
#define B_    16
#define NH_   12
#define HD_   64
#define NG_   4
#define BN_   (B_*NH_)                    // 192 chains
#define WX_T_STRIDE (BN_*HD_*NG_)         // 49152 floats per timestep
#define OUT_T_STRIDE (BN_*HD_)            // 12288 floats per timestep
#define OUT_S_STRIDE ((T_SEQ+1)*OUT_T_STRIDE)

typedef float v4f __attribute__((ext_vector_type(4)));

// raw workgroup barrier: orders LDS (lgkmcnt) but does NOT drain vmcnt —
// keeps the global prefetch ring in flight across steps.
#define LDS_BARRIER() asm volatile("s_waitcnt lgkmcnt(0)\n\ts_barrier" ::: "memory")

// pin: value becomes an asm output -> not rematerializable.
#define PIN4(x) asm volatile("" : "+v"(x))
#define PIN1(x) asm volatile("" : "+v"(x))

// DPP quad broadcast: all 4 lanes of the quad get lane L's value.
// quad_perm ctrl byte = L * 0x55. Builtin => compiler inserts hazard nops.
#define QB(x, CTRL) \
    __int_as_float(__builtin_amdgcn_update_dpp(0, __float_as_int(x), (CTRL), 0xF, 0xF, true))

// fused DPP add: dst = dpp<quad_perm>(srcA) + srcB  (one instruction).
// s_nop 1 = 2 wait states: covers the VALU-write -> DPP-read hazard on srcA
// (LLVM cannot see the DPP inside inline asm to insert these itself).
#define ADD_DPP_X1(dst, srcA, srcB)                                            \
    asm("s_nop 1\n\t"                                                          \
        "v_add_f32_dpp %0, %1, %2 quad_perm:[1,0,3,2] row_mask:0xf bank_mask:0xf" \
        : "=v"(dst) : "v"(srcA), "v"(srcB))
#define ADD_DPP_X2(dst, srcA, srcB)                                            \
    asm("s_nop 1\n\t"                                                          \
        "v_add_f32_dpp %0, %1, %2 quad_perm:[2,3,0,1] row_mask:0xf bank_mask:0xf" \
        : "=v"(dst) : "v"(srcA), "v"(srcB))

__device__ __forceinline__ float dot16(v4f a0, v4f a1, v4f a2, v4f a3,
                                       v4f h0, v4f h1, v4f h2, v4f h3)
{
    float p = a0.x * h0.x;
    p = fmaf(a0.y, h0.y, p); p = fmaf(a0.z, h0.z, p); p = fmaf(a0.w, h0.w, p);
    p = fmaf(a1.x, h1.x, p); p = fmaf(a1.y, h1.y, p);
    p = fmaf(a1.z, h1.z, p); p = fmaf(a1.w, h1.w, p);
    p = fmaf(a2.x, h2.x, p); p = fmaf(a2.y, h2.y, p);
    p = fmaf(a2.z, h2.z, p); p = fmaf(a2.w, h2.w, p);
    p = fmaf(a3.x, h3.x, p); p = fmaf(a3.y, h3.y, p);
    p = fmaf(a3.z, h3.z, p); p = fmaf(a3.w, h3.w, p);
    return p;
}

__global__ __launch_bounds__(256, 1) __attribute__((amdgpu_waves_per_eu(1)))
void flashrnn_lstm_fwd(const float* __restrict__ Wx,
                       const float* __restrict__ s0,
                       const float* __restrict__ R,
                       const float* __restrict__ bias,
                       float* __restrict__ out)
{
    const int bid = blockIdx.x;           // 0..191
    const int n   = bid % NH_;
    const int b   = bid / NH_;
    const int bn  = b*NH_ + n;
    const int tid = threadIdx.x;          // 0..255
    const int o   = tid >> 2;             // output index 0..63
    const int g   = tid & 3;              // gate 0..3 (i,f,z,o)

    __shared__ __align__(16) float hbuf[2][80];

    // --- R slices: accumulator m holds gate (g^m), columns [16g, 16g+16) ---
    const size_t rowstride = (size_t)HD_*HD_;
    const float* Rh = R + (size_t)n*NG_*rowstride + (size_t)o*HD_ + g*16;
    const v4f* RpA = (const v4f*)(Rh + (size_t)(g^0)*rowstride);
    const v4f* RpB = (const v4f*)(Rh + (size_t)(g^1)*rowstride);
    const v4f* RpC = (const v4f*)(Rh + (size_t)(g^2)*rowstride);
    const v4f* RpD = (const v4f*)(Rh + (size_t)(g^3)*rowstride);
    v4f r00 = RpA[0], r01 = RpA[1], r02 = RpA[2], r03 = RpA[3];
    v4f r10 = RpB[0], r11 = RpB[1], r12 = RpB[2], r13 = RpB[3];
    v4f r20 = RpC[0], r21 = RpC[1], r22 = RpC[2], r23 = RpC[3];
    v4f r30 = RpD[0], r31 = RpD[1], r32 = RpD[2], r33 = RpD[3];
    PIN4(r00); PIN4(r01); PIN4(r02); PIN4(r03);
    PIN4(r10); PIN4(r11); PIN4(r12); PIN4(r13);
    PIN4(r20); PIN4(r21); PIN4(r22); PIN4(r23);
    PIN4(r30); PIN4(r31); PIN4(r32); PIN4(r33);

    // unified activation: a = m * rcp(1 + exp2(s*x)) + k
    // g in {0,1,3}: sigmoid; g==2: tanh
    const float s_coef = (g == 2) ? -2.88539008f : -1.44269504f;
    const float m_coef = (g == 2) ? 2.0f : 1.0f;
    const float a_coef = (g == 2) ? -1.0f : 0.0f;

    float bval = bias[(n*NG_ + g)*HD_ + o];
    PIN1(bval);
    const float sbv = s_coef * bval;      // folded into swb each step

    // c state valid in ALL lanes (broadcast exchange below)
    float c = s0[BN_*HD_ + bn*HD_ + o];

    // --- init h in LDS buf 0 ---
    if (tid < 64) hbuf[0][tid] = s0[bn*HD_ + tid];

    // hoisted LDS pointers (compile-time selected per step parity)
    const v4f* hv0 = (const v4f*)&hbuf[0][g*16];
    const v4f* hv1 = (const v4f*)&hbuf[1][g*16];
    float* hw0 = &hbuf[1][o];             // CUR=0 writes buf1
    float* hw1 = &hbuf[0][o];             // CUR=1 writes buf0

    // software-pipelined output store: sv holds the value for row t, stored
    // at the TOP of the step computing t+1 (inside the LDS-read shadow).
    const bool isg1 = (g & 1) != 0;
    float sv = isg1 ? c : s0[bn*HD_ + o];               // t = 0 state
    const int ovofs = (isg1 ? OUT_S_STRIDE : 0) + o;    // per-lane, fixed
    float* ow = out + (size_t)bn*HD_;                   // uniform, walks

    // --- Wx prefetch ring (depth 4): per-lane offset = tid (fixed),
    //     4 uniform walking bases ---
    const float* wxp = Wx + (size_t)bn*(HD_*NG_);
    float wx0 = wxp[tid];
    float wx1 = wxp[(size_t)1 * WX_T_STRIDE + tid];
    float wx2 = wxp[(size_t)2 * WX_T_STRIDE + tid];
    float wx3 = wxp[(size_t)3 * WX_T_STRIDE + tid];
    const float* wb0 = wxp + (size_t)4 * WX_T_STRIDE;
    const float* wb1 = wxp + (size_t)5 * WX_T_STRIDE;
    const float* wb2 = wxp + (size_t)6 * WX_T_STRIDE;
    const float* wb3 = wxp + (size_t)7 * WX_T_STRIDE;

    __syncthreads();   // one full barrier before the loop (drains init loads)

// COMPUTE: dots -> hazard-guarded fused butterfly -> activation ->
// broadcast gates -> c update (+ parallel K*c for tanh) -> hval -> sv.
#define COMPUTE(HA, HB, HC, HD4, SWB)                                          \
        float p0 = dot16(r00, r01, r02, r03, HA, HB, HC, HD4);                 \
        float p1 = dot16(r10, r11, r12, r13, HA, HB, HC, HD4);                 \
        float p2 = dot16(r20, r21, r22, r23, HA, HB, HC, HD4);                 \
        float p3 = dot16(r30, r31, r32, r33, HA, HB, HC, HD4);                 \
        float q0, q2, d0;                                                      \
        ADD_DPP_X1(q0, p1, p0);          /* q0 = p0 + xor1(p1) */              \
        ADD_DPP_X1(q2, p3, p2);          /* q2 = p2 + xor1(p3) */              \
        ADD_DPP_X2(d0, q2, q0);          /* d0 = q0 + xor2(q2) — full dot */   \
        const float ev = __builtin_amdgcn_exp2f(fmaf(s_coef, d0, (SWB)));      \
        const float rv = __builtin_amdgcn_rcpf(1.0f + ev);                     \
        const float a  = fmaf(m_coef, rv, a_coef);                             \
        const float xi = QB(a, 0x00);    /* gate i = quad lane 0 */            \
        const float xf = QB(a, 0x55);    /* gate f = quad lane 1 */            \
        const float xz = QB(a, 0xAA);    /* gate z = quad lane 2 */            \
        const float xo = QB(a, 0xFF);    /* gate o = quad lane 3 */            \
        const float tmp = xi * xz;                                             \
        const float xfs = -2.88539008f * xf;                                   \
        const float ps  = -2.88539008f * tmp;                                  \
        const float m2c = fmaf(xfs, c, ps);   /* = K * c_new, from c_old */    \
        c = fmaf(xf, c, tmp);                                                  \
        const float e2  = __builtin_amdgcn_exp2f(m2c);                         \
        const float rv2 = __builtin_amdgcn_rcpf(1.0f + e2);                    \
        const float xo2 = xo + xo;                                             \
        const float hval = fmaf(xo2, rv2, -xo);  /* xo * tanh(c_new) */        \
        sv = isg1 ? c : hval;

// main-loop step: reads first, prev-store + prefetch + swb in the read shadow
#define STEP(SLOT, CUR)                                                        \
    {                                                                          \
        const v4f* hv = (CUR) ? hv1 : hv0;                                     \
        const v4f ha = hv[0], hb = hv[1], hcq = hv[2], hd4 = hv[3];            \
        if (g < 2) ow[ovofs] = sv;                                             \
        ow += OUT_T_STRIDE;                                                    \
        const float wxv = wx##SLOT;                                            \
        wx##SLOT = wb##SLOT[tid];                                              \
        wb##SLOT += (size_t)4 * WX_T_STRIDE;                                   \
        const float swb = fmaf(s_coef, wxv, sbv);                              \
        COMPUTE(ha, hb, hcq, hd4, swb)                                         \
        if (g == 0) *((CUR) ? hw1 : hw0) = hval;                               \
        LDS_BARRIER();                                                         \
    }

// epilogue step: no prefetch; LAST skips hbuf write + barrier
#define STEPE(SLOT, CUR, LAST)                                                 \
    {                                                                          \
        const v4f* hv = (CUR) ? hv1 : hv0;                                     \
        const v4f ha = hv[0], hb = hv[1], hcq = hv[2], hd4 = hv[3];            \
        if (g < 2) ow[ovofs] = sv;                                             \
        ow += OUT_T_STRIDE;                                                    \
        const float wxv = wx##SLOT;                                            \
        const float swb = fmaf(s_coef, wxv, sbv);                              \
        COMPUTE(ha, hb, hcq, hd4, swb)                                         \
        if (!(LAST)) {                                                         \
            if (g == 0) *((CUR) ? hw1 : hw0) = hval;                           \
            LDS_BARRIER();                                                     \
        }                                                                      \
    }

    for (int tb = 0; tb < T_SEQ-4; tb += 4) {
        // USE-pin: all 16 R tuples forced live, once per 4-step iteration
        asm volatile("" :: "v"(r00), "v"(r01), "v"(r02), "v"(r03),
                           "v"(r10), "v"(r11), "v"(r12), "v"(r13),
                           "v"(r20), "v"(r21), "v"(r22), "v"(r23),
                           "v"(r30), "v"(r31), "v"(r32), "v"(r33));
        STEP(0, 0)
        STEP(1, 1)
        STEP(2, 0)
        STEP(3, 1)
    }
    // epilogue: t = 1021..1024, consuming wx0..wx3 (= Wx[1020..1023])
    STEPE(0, 0, 0)
    STEPE(1, 1, 0)
    STEPE(2, 0, 0)
    STEPE(3, 1, 1)

    // final store: t = T_SEQ row
    if (g < 2) ow[ovofs] = sv;

#undef STEP
#undef STEPE
#undef COMPUTE
}

extern "C" void kernel_launch(void* const* d_in, const int* in_sizes, int n_in,
                              void* d_out, int out_size, void* d_ws, size_t ws_size,
                              hipStream_t stream) {
    const float* Wx = (const float*)d_in[0];
    const float* s0 = (const float*)d_in[1];
    const float* R  = (const float*)d_in[2];
    const float* bb = (const float*)d_in[3];
    float* out = (float*)d_out;
    flashrnn_lstm_fwd<<<dim3(BN_), dim3(256), 0, stream>>>(Wx, s0, R, bb, out);
}